// Round 7
// baseline (547.366 us; speedup 1.0000x reference)
//
#include <hip/hip_runtime.h>
#include <hip/hip_bf16.h>

typedef unsigned short u16;
typedef unsigned int u32;
typedef __attribute__((ext_vector_type(8))) short short8;   // bf16x8 MFMA frag (4 VGPR)
typedef __attribute__((ext_vector_type(4))) float float4v;  // fp32x4 acc
typedef __attribute__((ext_vector_type(4))) unsigned int uint4v; // 16B vector

__device__ __forceinline__ u16 f2bf(float f) {
    union { float f; unsigned int u; } v; v.f = f;
    unsigned int r = v.u + 0x7fffu + ((v.u >> 16) & 1u);  // RNE
    return (u16)(r >> 16);
}
__device__ __forceinline__ float bf2f(u16 h) {
    union { unsigned int u; float f; } v; v.u = ((unsigned int)h) << 16;
    return v.f;
}

// async 16B global -> LDS (lane i lands at ldsbase + i*16)
__device__ __forceinline__ void gld_lds16(const u16* g, u16* l) {
    __builtin_amdgcn_global_load_lds(
        (const __attribute__((address_space(1))) u32*)g,
        (__attribute__((address_space(3))) u32*)l, 16, 0, 0);
}

// ---------------------------------------------------------------------------
// x: fp32 [8192*1024] -> bf16. 8 elements/thread.
// ---------------------------------------------------------------------------
__global__ __launch_bounds__(256) void convert_x(
    const float* __restrict__ x, u16* __restrict__ xb) {
    int i = (blockIdx.x * 256 + threadIdx.x) * 8;
    float4v a = *(const float4v*)&x[i];
    float4v b = *(const float4v*)&x[i + 4];
    u16 tmp[8] __attribute__((aligned(16)));
#pragma unroll
    for (int j = 0; j < 4; ++j) { tmp[j] = f2bf(a[j]); tmp[4 + j] = f2bf(b[j]); }
    *(uint4v*)&xb[i] = *(uint4v*)tmp;
}

// ---------------------------------------------------------------------------
// Weight transpose+convert: W fp32 [1024][1024] (K x N) -> Wt bf16 (N x K).
// z = 0,1,2 -> rows z*1024 of wqkv_t[3072][1024]; z = 3 -> wto[1024][1024].
// ---------------------------------------------------------------------------
__global__ __launch_bounds__(256) void transpose_w(
    const float* __restrict__ w0, const float* __restrict__ w1,
    const float* __restrict__ w2, const float* __restrict__ w3,
    u16* __restrict__ wqkv, u16* __restrict__ wout) {
    __shared__ u16 t[32][33];
    int z = blockIdx.z;
    const float* w = (z == 0) ? w0 : (z == 1) ? w1 : (z == 2) ? w2 : w3;
    u16* o = (z == 3) ? wout : (wqkv + (size_t)z * 1024 * 1024);
    int bx = blockIdx.x * 32;   // input col (n)
    int by = blockIdx.y * 32;   // input row (k)
    int x = threadIdx.x, y = threadIdx.y;   // block (32,8)
#pragma unroll
    for (int i = 0; i < 4; ++i)
        t[y + i * 8][x] = f2bf(w[(size_t)(by + y + i * 8) * 1024 + bx + x]);
    __syncthreads();
#pragma unroll
    for (int i = 0; i < 4; ++i)
        o[(size_t)(bx + y + i * 8) * 1024 + by + x] = t[x][y + i * 8];
}

// ---------------------------------------------------------------------------
// Fused QKV GEMM: [8192][1024] @ wqkv_t[3072][1024]^T.  128x128 tile.
// n segment: [0,1024)->Q [M][1024]; [1024,2048)->K [M][1024];
// [2048,3072)->vt[(b*1024+c)*2048+n].
// ---------------------------------------------------------------------------
__global__ __launch_bounds__(256) void gemm_qkv(
    const u16* __restrict__ A, const u16* __restrict__ Bt,
    u16* __restrict__ Q, u16* __restrict__ Kb, u16* __restrict__ Vt, int K) {
    __shared__ __attribute__((aligned(16))) u16 As[128 * 32];
    __shared__ __attribute__((aligned(16))) u16 Bs[128 * 32];
    const int tid = threadIdx.x;
    const int m0 = blockIdx.y * 128;
    const int n0 = blockIdx.x * 128;
    const int wid = tid >> 6;
    const int lane = tid & 63;
    const int ln = lane & 15, kq = lane >> 4;
    const int wm = (wid >> 1) * 64, wn = (wid & 1) * 64;

    float4v acc[4][4] = {};
    for (int k0 = 0; k0 < K; k0 += 32) {
#pragma unroll
        for (int i = 0; i < 2; ++i) {
            int chunk = tid + i * 256;
            int row = chunk >> 2, cg = chunk & 3;
            u16* lA = &As[(size_t)(i * 256 + wid * 64) * 8];
            u16* lB = &Bs[(size_t)(i * 256 + wid * 64) * 8];
            gld_lds16(&A[(size_t)(m0 + row) * K + k0 + cg * 8], lA);
            gld_lds16(&Bt[(size_t)(n0 + row) * K + k0 + cg * 8], lB);
        }
        __syncthreads();
        short8 af[4], bfr[4];
#pragma unroll
        for (int mt = 0; mt < 4; ++mt)
            af[mt] = *(const short8*)&As[(wm + mt * 16 + ln) * 32 + kq * 8];
#pragma unroll
        for (int nt = 0; nt < 4; ++nt)
            bfr[nt] = *(const short8*)&Bs[(wn + nt * 16 + ln) * 32 + kq * 8];
#pragma unroll
        for (int mt = 0; mt < 4; ++mt)
#pragma unroll
            for (int nt = 0; nt < 4; ++nt)
                acc[mt][nt] = __builtin_amdgcn_mfma_f32_16x16x32_bf16(
                    af[mt], bfr[nt], acc[mt][nt], 0, 0, 0);
        __syncthreads();
    }
    if (n0 < 2048) {
        u16* C = (n0 < 1024) ? Q : Kb;
        int nb = n0 & 1023;
#pragma unroll
        for (int mt = 0; mt < 4; ++mt)
#pragma unroll
            for (int nt = 0; nt < 4; ++nt)
#pragma unroll
                for (int r = 0; r < 4; ++r) {
                    int row = m0 + wm + mt * 16 + kq * 4 + r;
                    int col = nb + wn + nt * 16 + ln;
                    C[(size_t)row * 1024 + col] = f2bf(acc[mt][nt][r]);
                }
    } else {
#pragma unroll
        for (int mt = 0; mt < 4; ++mt)
#pragma unroll
            for (int nt = 0; nt < 4; ++nt)
#pragma unroll
                for (int r = 0; r < 4; ++r) {
                    int t = m0 + wm + mt * 16 + kq * 4 + r;
                    int col = (n0 - 2048) + wn + nt * 16 + ln;
                    int b = t >> 11, n = t & 2047;
                    Vt[((size_t)(b * 1024 + col)) * 2048 + n] = f2bf(acc[mt][nt][r]);
                }
    }
}

// ---------------------------------------------------------------------------
// Output projection GEMM (bf16 in, fp32 out [M][N]).
// ---------------------------------------------------------------------------
__global__ __launch_bounds__(256) void gemm_out(
    const u16* __restrict__ A, const u16* __restrict__ Bt,
    float* __restrict__ C, int N, int K) {
    __shared__ __attribute__((aligned(16))) u16 As[128 * 32];
    __shared__ __attribute__((aligned(16))) u16 Bs[128 * 32];
    const int tid = threadIdx.x;
    const int m0 = blockIdx.y * 128;
    const int n0 = blockIdx.x * 128;
    const int wid = tid >> 6;
    const int lane = tid & 63;
    const int ln = lane & 15, kq = lane >> 4;
    const int wm = (wid >> 1) * 64, wn = (wid & 1) * 64;

    float4v acc[4][4] = {};
    for (int k0 = 0; k0 < K; k0 += 32) {
#pragma unroll
        for (int i = 0; i < 2; ++i) {
            int chunk = tid + i * 256;
            int row = chunk >> 2, cg = chunk & 3;
            u16* lA = &As[(size_t)(i * 256 + wid * 64) * 8];
            u16* lB = &Bs[(size_t)(i * 256 + wid * 64) * 8];
            gld_lds16(&A[(size_t)(m0 + row) * K + k0 + cg * 8], lA);
            gld_lds16(&Bt[(size_t)(n0 + row) * K + k0 + cg * 8], lB);
        }
        __syncthreads();
        short8 af[4], bfr[4];
#pragma unroll
        for (int mt = 0; mt < 4; ++mt)
            af[mt] = *(const short8*)&As[(wm + mt * 16 + ln) * 32 + kq * 8];
#pragma unroll
        for (int nt = 0; nt < 4; ++nt)
            bfr[nt] = *(const short8*)&Bs[(wn + nt * 16 + ln) * 32 + kq * 8];
#pragma unroll
        for (int mt = 0; mt < 4; ++mt)
#pragma unroll
            for (int nt = 0; nt < 4; ++nt)
                acc[mt][nt] = __builtin_amdgcn_mfma_f32_16x16x32_bf16(
                    af[mt], bfr[nt], acc[mt][nt], 0, 0, 0);
        __syncthreads();
    }
#pragma unroll
    for (int mt = 0; mt < 4; ++mt)
#pragma unroll
        for (int nt = 0; nt < 4; ++nt)
#pragma unroll
            for (int r = 0; r < 4; ++r) {
                int row = m0 + wm + mt * 16 + kq * 4 + r;
                int col = n0 + wn + nt * 16 + ln;
                C[(size_t)row * N + col] = acc[mt][nt][r];
            }
}

// ---------------------------------------------------------------------------
// Fused attention, head-axis softmax.  R7: R5-proven wave shape (1024 thr =
// 16 waves, wave = head wid, q-tile 32, E ping-pong, 2 barriers) + k-split x2
// + XCD swizzle.  Grid 512 1D: (b,kh) = bid&7 (presumed XCD id via bid%8),
// q0 = (bid>>3)*32.  Per-XCD K/V working set = 4 MB = its L2.
// ctx partials accumulated via packed-bf16 CAS into zeroed ctx buffer.
// ---------------------------------------------------------------------------
__global__ __launch_bounds__(1024) void attn_kernel(
    const u16* __restrict__ qb, const u16* __restrict__ kb,
    const u16* __restrict__ vt, u32* __restrict__ ctx) {
    __shared__ __attribute__((aligned(16))) u16 E[2][16 * 32 * 40]; // 81920 B
    __shared__ float Di[32 * 36];                                   //  4608 B

    const int bid = blockIdx.x;
    const int b  = (bid >> 1) & 3;      // batch
    const int kh = bid & 1;             // k-half
    const int q0 = (bid >> 3) * 32;     // q-tile
    const int tid = threadIdx.x;
    const int wid = tid >> 6, lane = tid & 63;   // wid 0..15 = head
    const int ln = lane & 15, kq = lane >> 4;
    const int h = wid;

    // Preload Q fragments for this wave's head
    short8 aq[2][2];   // [mt][kc]
#pragma unroll
    for (int mt = 0; mt < 2; ++mt)
#pragma unroll
        for (int kc = 0; kc < 2; ++kc)
            aq[mt][kc] = *(const short8*)&qb[
                (size_t)(b * 2048 + q0 + mt * 16 + ln) * 1024 +
                h * 64 + kc * 32 + kq * 8];

    float4v cacc[2][4] = {};   // [mt][nt] ctx accumulators (32q x 64d)

    const int kbeg = kh * 1024, kend = kbeg + 1024;
#pragma unroll 1
    for (int kt = kbeg; kt < kend; kt += 32) {
        const int cur = (kt >> 5) & 1;
        // ---- hoisted batched gathers: K (used now), V (used after 2 barriers)
        short8 bk[2][2];   // [kc][nt]
        short8 bv[4];      // [nt]
#pragma unroll
        for (int kc = 0; kc < 2; ++kc)
#pragma unroll
            for (int nt = 0; nt < 2; ++nt)
                bk[kc][nt] = *(const short8*)&kb[
                    (size_t)(b * 2048 + kt + nt * 16 + ln) * 1024 +
                    h * 64 + kc * 32 + kq * 8];
#pragma unroll
        for (int nt = 0; nt < 4; ++nt)
            bv[nt] = *(const short8*)&vt[
                (size_t)(b * 1024 + h * 64 + nt * 16 + ln) * 2048 + kt + kq * 8];

        // ---- S = Q @ K^T for this head
        float4v sacc[2][2] = {};   // [mt][nt]
#pragma unroll
        for (int kc = 0; kc < 2; ++kc)
#pragma unroll
            for (int mt = 0; mt < 2; ++mt)
#pragma unroll
                for (int nt = 0; nt < 2; ++nt)
                    sacc[mt][nt] = __builtin_amdgcn_mfma_f32_16x16x32_bf16(
                        aq[mt][kc], bk[kc][nt], sacc[mt][nt], 0, 0, 0);

        // ---- E = exp(S*scale) -> ping-pong buffer (E[cur] last read in
        // Phase D two iterations ago, past 2 barriers)
#pragma unroll
        for (int mt = 0; mt < 2; ++mt)
#pragma unroll
            for (int nt = 0; nt < 2; ++nt)
#pragma unroll
                for (int r = 0; r < 4; ++r) {
                    // exp(s/8) = exp2(s * log2(e)/8)
                    float s = sacc[mt][nt][r] * 0.18033688f;
                    E[cur][(h * 32 + mt * 16 + kq * 4 + r) * 40 + nt * 16 + ln] =
                        f2bf(exp2f(fminf(s, 115.0f)));
                }
        __syncthreads();   // BAR-A: E[cur] complete

        // ---- Dinv = 1 / sum_h E  (1024 threads, one (q,k) each)
        {
            int q = tid >> 5, kk = tid & 31;
            float d = 0.f;
#pragma unroll
            for (int hh = 0; hh < 16; ++hh)
                d += bf2f(E[cur][(hh * 32 + q) * 40 + kk]);
            Di[q * 36 + kk] = __builtin_amdgcn_rcpf(d);
        }
        __syncthreads();   // BAR-B: Di complete

        // ---- ctx += (E * Dinv) @ V
        short8 ap[2];
#pragma unroll
        for (int mt = 0; mt < 2; ++mt) {
            const u16* ep = &E[cur][(h * 32 + mt * 16 + ln) * 40 + kq * 8];
            const float* dp = &Di[(mt * 16 + ln) * 36 + kq * 8];
            u16 tmp[8] __attribute__((aligned(16)));
#pragma unroll
            for (int j = 0; j < 8; ++j)
                tmp[j] = f2bf(bf2f(ep[j]) * dp[j]);
            ap[mt] = *(short8*)tmp;
        }
#pragma unroll
        for (int nt = 0; nt < 4; ++nt)
#pragma unroll
            for (int mt = 0; mt < 2; ++mt)
                cacc[mt][nt] = __builtin_amdgcn_mfma_f32_16x16x32_bf16(
                    ap[mt], bv[nt], cacc[mt][nt], 0, 0, 0);
    }

    // Epilogue: accumulate partial ctx via packed-bf16 CAS.  Lane pairs
    // (ln even/odd) hold adjacent cols of the same row; pack via shfl_xor.
#pragma unroll
    for (int mt = 0; mt < 2; ++mt)
#pragma unroll
        for (int nt = 0; nt < 4; ++nt)
#pragma unroll
            for (int r = 0; r < 4; ++r) {
                float v = cacc[mt][nt][r];
                float v2 = __shfl_xor(v, 1);     // partner col's value
                if ((lane & 1) == 0) {
                    int row = b * 2048 + q0 + mt * 16 + kq * 4 + r;
                    int col = h * 64 + nt * 16 + ln;   // even
                    u32* addr = &ctx[((size_t)row * 1024 + col) >> 1];
                    u32 old = __hip_atomic_load(addr, __ATOMIC_RELAXED,
                                                __HIP_MEMORY_SCOPE_AGENT);
                    u32 assumed;
                    do {
                        assumed = old;
                        float lo = bf2f((u16)(assumed & 0xffff)) + v;
                        float hi = bf2f((u16)(assumed >> 16)) + v2;
                        u32 nv = ((u32)f2bf(hi) << 16) | (u32)f2bf(lo);
                        old = atomicCAS(addr, assumed, nv);
                    } while (old != assumed);
                }
            }
}

// ---------------------------------------------------------------------------
extern "C" void kernel_launch(void* const* d_in, const int* in_sizes, int n_in,
                              void* d_out, int out_size, void* d_ws, size_t ws_size,
                              hipStream_t stream) {
    const float* x   = (const float*)d_in[0];   // [8192][1024] fp32
    const float* w_q = (const float*)d_in[1];   // [1024][1024] fp32 (K x N)
    const float* w_k = (const float*)d_in[2];
    const float* w_v = (const float*)d_in[3];
    const float* w_o = (const float*)d_in[4];

    char* ws = (char*)d_ws;
    const size_t SZ_TOK = (size_t)8192 * 1024 * 2;   // 16 MiB
    // ws layout (40 MiB): [0,16) x_bf -> later ctx | [16,22) wqkv_t |
    // [22,24) wto | [24,40) q_buf
    u16* x_bf   = (u16*)(ws);
    u16* ctx    = (u16*)(ws);                        // reuses x_bf after QKV
    u16* wqkv_t = (u16*)(ws + SZ_TOK);
    u16* wto    = (u16*)(ws + SZ_TOK + (size_t)3 * 1024 * 1024 * 2);
    u16* q_buf  = (u16*)(ws + SZ_TOK + (size_t)4 * 1024 * 1024 * 2);
    // k_buf / vt_buf live in d_out (32 MiB fp32) — dead before final GEMM
    u16* k_buf  = (u16*)d_out;
    u16* vt_buf = (u16*)d_out + (size_t)8192 * 1024;

    // 0. convert x to bf16
    convert_x<<<4096, 256, 0, stream>>>(x, x_bf);

    // 1. transpose+convert weights (q,k,v stacked into wqkv_t[3072][1024])
    transpose_w<<<dim3(32, 32, 4), dim3(32, 8), 0, stream>>>(
        w_q, w_k, w_v, w_o, wqkv_t, wto);

    // 2. fused QKV projection (V written directly transposed per batch)
    gemm_qkv<<<dim3(24, 64), 256, 0, stream>>>(
        x_bf, wqkv_t, q_buf, k_buf, vt_buf, 1024);

    // 3. zero ctx accumulator (x_bf now dead), then attention
    hipMemsetAsync(ctx, 0, SZ_TOK, stream);
    attn_kernel<<<512, 1024, 0, stream>>>(q_buf, k_buf, vt_buf, (u32*)ctx);

    // 4. output projection -> fp32 d_out (overwrites k_buf/vt_buf scratch)
    gemm_out<<<dim3(8, 64), 256, 0, stream>>>(ctx, wto, (float*)d_out, 1024, 1024);
}

// Round 8
// 539.879 us; speedup vs baseline: 1.0139x; 1.0139x over previous
//
#include <hip/hip_runtime.h>
#include <hip/hip_bf16.h>

typedef unsigned short u16;
typedef unsigned int u32;
typedef __attribute__((ext_vector_type(8))) short short8;   // bf16x8 MFMA frag (4 VGPR)
typedef __attribute__((ext_vector_type(4))) float float4v;  // fp32x4 acc
typedef __attribute__((ext_vector_type(4))) unsigned int uint4v; // 16B vector

__device__ __forceinline__ u16 f2bf(float f) {
    union { float f; unsigned int u; } v; v.f = f;
    unsigned int r = v.u + 0x7fffu + ((v.u >> 16) & 1u);  // RNE
    return (u16)(r >> 16);
}
__device__ __forceinline__ u32 fbits(float f) {
    union { float f; u32 u; } v; v.f = f; return v.u;
}
// pack two fp32 -> bf16x2 dword by truncation (lo = a, hi = b)
__device__ __forceinline__ u32 pack_bf2_trunc(float a, float b) {
    return (fbits(a) >> 16) | (fbits(b) & 0xffff0000u);
}

// async 16B global -> LDS (lane i lands at ldsbase + i*16)
__device__ __forceinline__ void gld_lds16(const u16* g, u16* l) {
    __builtin_amdgcn_global_load_lds(
        (const __attribute__((address_space(1))) u32*)g,
        (__attribute__((address_space(3))) u32*)l, 16, 0, 0);
}

// ---------------------------------------------------------------------------
// x: fp32 [8192*1024] -> bf16. 8 elements/thread.
// ---------------------------------------------------------------------------
__global__ __launch_bounds__(256) void convert_x(
    const float* __restrict__ x, u16* __restrict__ xb) {
    int i = (blockIdx.x * 256 + threadIdx.x) * 8;
    float4v a = *(const float4v*)&x[i];
    float4v b = *(const float4v*)&x[i + 4];
    u16 tmp[8] __attribute__((aligned(16)));
#pragma unroll
    for (int j = 0; j < 4; ++j) { tmp[j] = f2bf(a[j]); tmp[4 + j] = f2bf(b[j]); }
    *(uint4v*)&xb[i] = *(uint4v*)tmp;
}

// ---------------------------------------------------------------------------
// Weight transpose+convert: W fp32 [1024][1024] (K x N) -> Wt bf16 (N x K).
// z = 0,1,2 -> rows z*1024 of wqkv_t[3072][1024]; z = 3 -> wto[1024][1024].
// ---------------------------------------------------------------------------
__global__ __launch_bounds__(256) void transpose_w(
    const float* __restrict__ w0, const float* __restrict__ w1,
    const float* __restrict__ w2, const float* __restrict__ w3,
    u16* __restrict__ wqkv, u16* __restrict__ wout) {
    __shared__ u16 t[32][33];
    int z = blockIdx.z;
    const float* w = (z == 0) ? w0 : (z == 1) ? w1 : (z == 2) ? w2 : w3;
    u16* o = (z == 3) ? wout : (wqkv + (size_t)z * 1024 * 1024);
    int bx = blockIdx.x * 32;   // input col (n)
    int by = blockIdx.y * 32;   // input row (k)
    int x = threadIdx.x, y = threadIdx.y;   // block (32,8)
#pragma unroll
    for (int i = 0; i < 4; ++i)
        t[y + i * 8][x] = f2bf(w[(size_t)(by + y + i * 8) * 1024 + bx + x]);
    __syncthreads();
#pragma unroll
    for (int i = 0; i < 4; ++i)
        o[(size_t)(bx + y + i * 8) * 1024 + by + x] = t[x][y + i * 8];
}

// ---------------------------------------------------------------------------
// Fused QKV GEMM: [8192][1024] @ wqkv_t[3072][1024]^T.  128x128 tile.
// n segment: [0,1024)->Q [M][1024]; [1024,2048)->K [M][1024];
// [2048,3072)->vt[(b*1024+c)*2048+n].
// ---------------------------------------------------------------------------
__global__ __launch_bounds__(256) void gemm_qkv(
    const u16* __restrict__ A, const u16* __restrict__ Bt,
    u16* __restrict__ Q, u16* __restrict__ Kb, u16* __restrict__ Vt, int K) {
    __shared__ __attribute__((aligned(16))) u16 As[128 * 32];
    __shared__ __attribute__((aligned(16))) u16 Bs[128 * 32];
    const int tid = threadIdx.x;
    const int m0 = blockIdx.y * 128;
    const int n0 = blockIdx.x * 128;
    const int wid = tid >> 6;
    const int lane = tid & 63;
    const int ln = lane & 15, kq = lane >> 4;
    const int wm = (wid >> 1) * 64, wn = (wid & 1) * 64;

    float4v acc[4][4] = {};
    for (int k0 = 0; k0 < K; k0 += 32) {
#pragma unroll
        for (int i = 0; i < 2; ++i) {
            int chunk = tid + i * 256;
            int row = chunk >> 2, cg = chunk & 3;
            u16* lA = &As[(size_t)(i * 256 + wid * 64) * 8];
            u16* lB = &Bs[(size_t)(i * 256 + wid * 64) * 8];
            gld_lds16(&A[(size_t)(m0 + row) * K + k0 + cg * 8], lA);
            gld_lds16(&Bt[(size_t)(n0 + row) * K + k0 + cg * 8], lB);
        }
        __syncthreads();
        short8 af[4], bfr[4];
#pragma unroll
        for (int mt = 0; mt < 4; ++mt)
            af[mt] = *(const short8*)&As[(wm + mt * 16 + ln) * 32 + kq * 8];
#pragma unroll
        for (int nt = 0; nt < 4; ++nt)
            bfr[nt] = *(const short8*)&Bs[(wn + nt * 16 + ln) * 32 + kq * 8];
#pragma unroll
        for (int mt = 0; mt < 4; ++mt)
#pragma unroll
            for (int nt = 0; nt < 4; ++nt)
                acc[mt][nt] = __builtin_amdgcn_mfma_f32_16x16x32_bf16(
                    af[mt], bfr[nt], acc[mt][nt], 0, 0, 0);
        __syncthreads();
    }
    if (n0 < 2048) {
        u16* C = (n0 < 1024) ? Q : Kb;
        int nb = n0 & 1023;
#pragma unroll
        for (int mt = 0; mt < 4; ++mt)
#pragma unroll
            for (int nt = 0; nt < 4; ++nt)
#pragma unroll
                for (int r = 0; r < 4; ++r) {
                    int row = m0 + wm + mt * 16 + kq * 4 + r;
                    int col = nb + wn + nt * 16 + ln;
                    C[(size_t)row * 1024 + col] = f2bf(acc[mt][nt][r]);
                }
    } else {
#pragma unroll
        for (int mt = 0; mt < 4; ++mt)
#pragma unroll
            for (int nt = 0; nt < 4; ++nt)
#pragma unroll
                for (int r = 0; r < 4; ++r) {
                    int t = m0 + wm + mt * 16 + kq * 4 + r;
                    int col = (n0 - 2048) + wn + nt * 16 + ln;
                    int b = t >> 11, n = t & 2047;
                    Vt[((size_t)(b * 1024 + col)) * 2048 + n] = f2bf(acc[mt][nt][r]);
                }
    }
}

// ---------------------------------------------------------------------------
// Output projection GEMM (bf16 in, fp32 out [M][N]).
// ---------------------------------------------------------------------------
__global__ __launch_bounds__(256) void gemm_out(
    const u16* __restrict__ A, const u16* __restrict__ Bt,
    float* __restrict__ C, int N, int K) {
    __shared__ __attribute__((aligned(16))) u16 As[128 * 32];
    __shared__ __attribute__((aligned(16))) u16 Bs[128 * 32];
    const int tid = threadIdx.x;
    const int m0 = blockIdx.y * 128;
    const int n0 = blockIdx.x * 128;
    const int wid = tid >> 6;
    const int lane = tid & 63;
    const int ln = lane & 15, kq = lane >> 4;
    const int wm = (wid >> 1) * 64, wn = (wid & 1) * 64;

    float4v acc[4][4] = {};
    for (int k0 = 0; k0 < K; k0 += 32) {
#pragma unroll
        for (int i = 0; i < 2; ++i) {
            int chunk = tid + i * 256;
            int row = chunk >> 2, cg = chunk & 3;
            u16* lA = &As[(size_t)(i * 256 + wid * 64) * 8];
            u16* lB = &Bs[(size_t)(i * 256 + wid * 64) * 8];
            gld_lds16(&A[(size_t)(m0 + row) * K + k0 + cg * 8], lA);
            gld_lds16(&Bt[(size_t)(n0 + row) * K + k0 + cg * 8], lB);
        }
        __syncthreads();
        short8 af[4], bfr[4];
#pragma unroll
        for (int mt = 0; mt < 4; ++mt)
            af[mt] = *(const short8*)&As[(wm + mt * 16 + ln) * 32 + kq * 8];
#pragma unroll
        for (int nt = 0; nt < 4; ++nt)
            bfr[nt] = *(const short8*)&Bs[(wn + nt * 16 + ln) * 32 + kq * 8];
#pragma unroll
        for (int mt = 0; mt < 4; ++mt)
#pragma unroll
            for (int nt = 0; nt < 4; ++nt)
                acc[mt][nt] = __builtin_amdgcn_mfma_f32_16x16x32_bf16(
                    af[mt], bfr[nt], acc[mt][nt], 0, 0, 0);
        __syncthreads();
    }
#pragma unroll
    for (int mt = 0; mt < 4; ++mt)
#pragma unroll
        for (int nt = 0; nt < 4; ++nt)
#pragma unroll
            for (int r = 0; r < 4; ++r) {
                int row = m0 + wm + mt * 16 + kq * 4 + r;
                int col = n0 + wn + nt * 16 + ln;
                C[(size_t)row * N + col] = acc[mt][nt][r];
            }
}

// ---------------------------------------------------------------------------
// Fused attention, head-axis softmax.  R8: VALU/LDS diet on R5 skeleton.
// 1024 thr = 16 waves = 16 heads, q-tile 32, 256 blocks, plain ctx stores.
// E fp32 ping-pong [2][16][32][36] (147.5 KB) + Di fp32 [32][36] -> no
// bf16 conversions in E-store/Dinv; Dinv + repack fully b128-vectorized;
// P packed to bf16 by truncation (2 ops/pair).  bk prefetched 1 iter ahead.
// qb/cb distinct buffers (no aliasing constraints).
// ---------------------------------------------------------------------------
__global__ __launch_bounds__(1024) void attn_kernel(
    const u16* __restrict__ qb, const u16* __restrict__ kb,
    const u16* __restrict__ vt, u16* __restrict__ cb) {
    __shared__ float E[2][16 * 32 * 36];   // 147456 B
    __shared__ float Di[32 * 36];          //   4608 B

    const int b = blockIdx.y;
    const int q0 = blockIdx.x * 32;
    const int tid = threadIdx.x;
    const int wid = tid >> 6, lane = tid & 63;   // wid 0..15 = head
    const int ln = lane & 15, kq = lane >> 4;
    const int h = wid;

    // Preload Q fragments for this wave's head
    short8 aq[2][2];   // [mt][kc]
#pragma unroll
    for (int mt = 0; mt < 2; ++mt)
#pragma unroll
        for (int kc = 0; kc < 2; ++kc)
            aq[mt][kc] = *(const short8*)&qb[
                (size_t)(b * 2048 + q0 + mt * 16 + ln) * 1024 +
                h * 64 + kc * 32 + kq * 8];

    float4v cacc[2][4] = {};   // [mt][nt] ctx accumulators (32q x 64d)

    // prefetch bk for kt = 0
    short8 bk_cur[2][2], bk_nxt[2][2];   // [kc][nt]
#pragma unroll
    for (int kc = 0; kc < 2; ++kc)
#pragma unroll
        for (int nt = 0; nt < 2; ++nt)
            bk_cur[kc][nt] = *(const short8*)&kb[
                (size_t)(b * 2048 + 0 + nt * 16 + ln) * 1024 +
                h * 64 + kc * 32 + kq * 8];

#pragma unroll 1
    for (int kt = 0; kt < 2048; kt += 32) {
        const int cur = (kt >> 5) & 1;
        const int ktn = (kt + 32 < 2048) ? kt + 32 : 0;   // dummy on last iter

        // ---- issue next-iter K prefetch + current V loads (V used in phase D)
        short8 bv[4];      // [nt] d-tiles
#pragma unroll
        for (int kc = 0; kc < 2; ++kc)
#pragma unroll
            for (int nt = 0; nt < 2; ++nt)
                bk_nxt[kc][nt] = *(const short8*)&kb[
                    (size_t)(b * 2048 + ktn + nt * 16 + ln) * 1024 +
                    h * 64 + kc * 32 + kq * 8];
#pragma unroll
        for (int nt = 0; nt < 4; ++nt)
            bv[nt] = *(const short8*)&vt[
                (size_t)(b * 1024 + h * 64 + nt * 16 + ln) * 2048 + kt + kq * 8];

        // ---- S = Q @ K^T for this head (bk_cur already resident)
        float4v sacc[2][2] = {};   // [mt][nt]
#pragma unroll
        for (int kc = 0; kc < 2; ++kc)
#pragma unroll
            for (int mt = 0; mt < 2; ++mt)
#pragma unroll
                for (int nt = 0; nt < 2; ++nt)
                    sacc[mt][nt] = __builtin_amdgcn_mfma_f32_16x16x32_bf16(
                        aq[mt][kc], bk_cur[kc][nt], sacc[mt][nt], 0, 0, 0);

        // ---- E = exp(S*scale) fp32 -> ping-pong (E[cur] last read 2 barriers ago)
#pragma unroll
        for (int mt = 0; mt < 2; ++mt)
#pragma unroll
            for (int nt = 0; nt < 2; ++nt)
#pragma unroll
                for (int r = 0; r < 4; ++r) {
                    // exp(s/8) = exp2(s * log2(e)/8)
                    float s = sacc[mt][nt][r] * 0.18033688f;
                    E[cur][(h * 32 + mt * 16 + kq * 4 + r) * 36 + nt * 16 + ln] =
                        exp2f(fminf(s, 115.0f));
                }
        __syncthreads();   // BAR-A: E[cur] complete; Di free to overwrite

        // ---- Dinv = 1 / sum_h E : 256 threads, float4 per thread
        if (tid < 256) {
            int q = tid >> 3, k4 = (tid & 7) * 4;
            float4v s4 = {};
#pragma unroll
            for (int hh = 0; hh < 16; ++hh)
                s4 += *(const float4v*)&E[cur][(hh * 32 + q) * 36 + k4];
            float4v r4;
#pragma unroll
            for (int j = 0; j < 4; ++j) r4[j] = __builtin_amdgcn_rcpf(s4[j]);
            *(float4v*)&Di[q * 36 + k4] = r4;
        }
        __syncthreads();   // BAR-B: Di complete

        // ---- ctx += (E * Dinv) @ V  (vectorized repack, trunc pack)
        short8 ap[2];
#pragma unroll
        for (int mt = 0; mt < 2; ++mt) {
            const float* ep = &E[cur][(h * 32 + mt * 16 + ln) * 36 + kq * 8];
            const float* dp = &Di[(mt * 16 + ln) * 36 + kq * 8];
            float4v e0 = *(const float4v*)ep;
            float4v e1 = *(const float4v*)(ep + 4);
            float4v d0 = *(const float4v*)dp;
            float4v d1 = *(const float4v*)(dp + 4);
            float4v p0 = e0 * d0, p1 = e1 * d1;
            uint4v w;
            w.x = pack_bf2_trunc(p0.x, p0.y);
            w.y = pack_bf2_trunc(p0.z, p0.w);
            w.z = pack_bf2_trunc(p1.x, p1.y);
            w.w = pack_bf2_trunc(p1.z, p1.w);
            union { uint4v u; short8 s; } cvt; cvt.u = w;
            ap[mt] = cvt.s;
        }
#pragma unroll
        for (int nt = 0; nt < 4; ++nt)
#pragma unroll
            for (int mt = 0; mt < 2; ++mt)
                cacc[mt][nt] = __builtin_amdgcn_mfma_f32_16x16x32_bf16(
                    ap[mt], bv[nt], cacc[mt][nt], 0, 0, 0);

        // ---- rotate prefetched K registers
#pragma unroll
        for (int kc = 0; kc < 2; ++kc)
#pragma unroll
            for (int nt = 0; nt < 2; ++nt)
                bk_cur[kc][nt] = bk_nxt[kc][nt];
    }

    // Epilogue: ctx[b*2048+q][h*64+d], bf16
#pragma unroll
    for (int mt = 0; mt < 2; ++mt)
#pragma unroll
        for (int nt = 0; nt < 4; ++nt)
#pragma unroll
            for (int r = 0; r < 4; ++r) {
                int row = b * 2048 + q0 + mt * 16 + kq * 4 + r;
                int col = h * 64 + nt * 16 + ln;
                cb[(size_t)row * 1024 + col] = f2bf(cacc[mt][nt][r]);
            }
}

// ---------------------------------------------------------------------------
extern "C" void kernel_launch(void* const* d_in, const int* in_sizes, int n_in,
                              void* d_out, int out_size, void* d_ws, size_t ws_size,
                              hipStream_t stream) {
    const float* x   = (const float*)d_in[0];   // [8192][1024] fp32
    const float* w_q = (const float*)d_in[1];   // [1024][1024] fp32 (K x N)
    const float* w_k = (const float*)d_in[2];
    const float* w_v = (const float*)d_in[3];
    const float* w_o = (const float*)d_in[4];

    char* ws = (char*)d_ws;
    const size_t SZ_TOK = (size_t)8192 * 1024 * 2;   // 16 MiB
    // ws layout (40 MiB): [0,16) x_bf -> later ctx | [16,22) wqkv_t |
    // [22,24) wto | [24,40) q_buf
    u16* x_bf   = (u16*)(ws);
    u16* ctx    = (u16*)(ws);                        // reuses x_bf after QKV
    u16* wqkv_t = (u16*)(ws + SZ_TOK);
    u16* wto    = (u16*)(ws + SZ_TOK + (size_t)3 * 1024 * 1024 * 2);
    u16* q_buf  = (u16*)(ws + SZ_TOK + (size_t)4 * 1024 * 1024 * 2);
    // k_buf / vt_buf live in d_out (32 MiB fp32) — dead before final GEMM
    u16* k_buf  = (u16*)d_out;
    u16* vt_buf = (u16*)d_out + (size_t)8192 * 1024;

    // 0. convert x to bf16
    convert_x<<<4096, 256, 0, stream>>>(x, x_bf);

    // 1. transpose+convert weights (q,k,v stacked into wqkv_t[3072][1024])
    transpose_w<<<dim3(32, 32, 4), dim3(32, 8), 0, stream>>>(
        w_q, w_k, w_v, w_o, wqkv_t, wto);

    // 2. fused QKV projection (V written directly transposed per batch)
    gemm_qkv<<<dim3(24, 64), 256, 0, stream>>>(
        x_bf, wqkv_t, q_buf, k_buf, vt_buf, 1024);

    // 3. fused attention with head-axis softmax (ctx overwrites x_bf region)
    attn_kernel<<<dim3(64, 4), 1024, 0, stream>>>(q_buf, k_buf, vt_buf, ctx);

    // 4. output projection -> fp32 d_out (overwrites k_buf/vt_buf scratch)
    gemm_out<<<dim3(8, 64), 256, 0, stream>>>(ctx, wto, (float*)d_out, 1024, 1024);
}